// Round 1
// 1639.419 us; speedup vs baseline: 1.0246x; 1.0246x over previous
//
#include <hip/hip_runtime.h>
#include <cstdint>

#define N_ROWS   262144
#define DIMX     1024
#define HIDX     256
#define NSEG     2048
#define BLK_M    64
#define KSTEPS   32      // 1024 / 32

typedef __attribute__((ext_vector_type(4))) float  floatx4;
typedef __bf16 bf16x8 __attribute__((ext_vector_type(8)));

__device__ __forceinline__ unsigned short f2bf(float f) {
  unsigned int u = __float_as_uint(f);
  u += 0x7fffu + ((u >> 16) & 1u);          // round-to-nearest-even
  return (unsigned short)(u >> 16);
}

__device__ __forceinline__ unsigned int pk2(float a, float b) {
  return (unsigned int)f2bf(a) | ((unsigned int)f2bf(b) << 16);
}

// tanh(x) = 1 - 2/(e^{2x}+1); branch-free, correct at +/-inf overflow.
__device__ __forceinline__ float tanh_fast(float v) {
  float e = __expf(2.0f * v);
  return 1.0f - 2.0f / (e + 1.0f);
}

// ---------------------------------------------------------------------------
// prep: (a) W1 fp32 -> bf16 swizzled to B-fragment-ready layout [k/8][n][8]
//       (b) segment start offsets via binary search on sorted batch
// Thread owns (kb, n): reads 8 k-values (coalesced across n), writes one
// contiguous 16B chunk of w1s (coalesced).
// ---------------------------------------------------------------------------
__global__ __launch_bounds__(256) void prep_kernel(
    const float* __restrict__ W1, const int* __restrict__ batch,
    unsigned short* __restrict__ w1s, int* __restrict__ segs)
{
  int gid = blockIdx.x * 256 + threadIdx.x;   // 0 .. 32767
  int n  = gid & 255;
  int kb = gid >> 8;                          // 0 .. 127
  float v[8];
  #pragma unroll
  for (int j = 0; j < 8; ++j)
    v[j] = W1[(size_t)(kb * 8 + j) * 256 + n];
  uint4 pk = make_uint4(pk2(v[0], v[1]), pk2(v[2], v[3]),
                        pk2(v[4], v[5]), pk2(v[6], v[7]));
  *(uint4*)(w1s + ((size_t)(kb * 256 + n) << 3)) = pk;

  if (gid <= NSEG) {
    int lo = 0, hi = N_ROWS;
    while (lo < hi) {
      int mid = (lo + hi) >> 1;
      if (batch[mid] < gid) lo = mid + 1; else hi = mid;
    }
    segs[gid] = lo;
  }
}

// ---------------------------------------------------------------------------
// score: per 64-row block compute s = tanh(x@W1 + b1) @ W2 + b2, ew = exp(s)
// 4 waves, each owns 64 HID columns; wave tile 64x64 via mfma 16x16x32 bf16.
// A (x rows): fp32->bf16 in regs -> LDS frag-ready [kb][m][8]
//   COALESCED staging: 4 lanes cover one row's 128B k-window (m = tid>>2,
//   kb = tid&3) so a wave load covers 16 x 128B fully-used segments, not a
//   64-line 4KB-stride gather.
// B (W1):     global_load_lds dwordx4 from pre-swizzled w1s (L2-resident)
// ---------------------------------------------------------------------------
__global__ __launch_bounds__(256) void score_kernel(
    const float* __restrict__ x, const unsigned short* __restrict__ w1s,
    const float* __restrict__ b1, const float* __restrict__ w2,
    const float* __restrict__ b2, float* __restrict__ ew)
{
  __shared__ __align__(16) unsigned short Abf[4][64][8];    // 4 KB
  __shared__ __align__(16) unsigned short Bbf[4][256][8];   // 16 KB
  __shared__ float sred[64][4];                             // 1 KB

  const int tid  = threadIdx.x;
  const int lane = tid & 63;
  const int wv   = tid >> 6;        // wave id = HID column group
  const int l15  = lane & 15;
  const int q    = lane >> 4;       // MFMA quad
  const int row_base = blockIdx.x * BLK_M;

  // A staging map: thread stages row (tid>>2), k-subblock (tid&3)
  const int m_a  = tid >> 2;
  const int kb_a = tid & 3;
  const float* aptr = x + (size_t)(row_base + m_a) * DIMX + kb_a * 8;

  floatx4 acc[4][4] = {};   // h[64 rows][this wave's 64 cols]

  for (int ks = 0; ks < KSTEPS; ++ks) {
    // ---- B stage: 16 KB DMA, lane-contiguous (pre-swizzled source) ----
    const unsigned short* bsrc = w1s + (size_t)ks * (4 * 256 * 8);
    #pragma unroll
    for (int c = 0; c < 4; ++c) {
      __builtin_amdgcn_global_load_lds(
          (const __attribute__((address_space(1))) void*)(bsrc + c * 2048 + tid * 8),
          (__attribute__((address_space(3))) void*)(&Bbf[c][0][0] + tid * 8),
          16, 0, 0);
    }
    // ---- A stage: 8 fp32 -> 8 bf16, one 16B LDS store ----
    float4 fa = *(const float4*)(aptr);
    float4 fb = *(const float4*)(aptr + 4);
    aptr += 32;
    uint4 pk = make_uint4(pk2(fa.x, fa.y), pk2(fa.z, fa.w),
                          pk2(fb.x, fb.y), pk2(fb.z, fb.w));
    *(uint4*)(&Abf[kb_a][m_a][0]) = pk;
    __syncthreads();

    // ---- fragments: conflict-free sequential ds_read_b128 ----
    bf16x8 af[4], bfr[4];
    #pragma unroll
    for (int mt = 0; mt < 4; ++mt)
      af[mt] = *(const bf16x8*)(&Abf[q][mt * 16 + l15][0]);
    #pragma unroll
    for (int nt = 0; nt < 4; ++nt)
      bfr[nt] = *(const bf16x8*)(&Bbf[q][wv * 64 + nt * 16 + l15][0]);
    #pragma unroll
    for (int mt = 0; mt < 4; ++mt)
      #pragma unroll
      for (int nt = 0; nt < 4; ++nt)
        acc[mt][nt] = __builtin_amdgcn_mfma_f32_16x16x32_bf16(
            af[mt], bfr[nt], acc[mt][nt], 0, 0, 0);
    __syncthreads();
  }

  // ---- epilogue: s_row = sum_cols tanh(h + b1) * W2 ----
  float w2c[4], b1c[4];
  #pragma unroll
  for (int nt = 0; nt < 4; ++nt) {
    int col = wv * 64 + nt * 16 + l15;
    w2c[nt] = w2[col];
    b1c[nt] = b1[col];
  }
  #pragma unroll
  for (int mt = 0; mt < 4; ++mt) {
    #pragma unroll
    for (int r = 0; r < 4; ++r) {
      // C/D layout: col = lane&15, row = (lane>>4)*4 + reg   [m89/m91]
      float p = 0.f;
      #pragma unroll
      for (int nt = 0; nt < 4; ++nt)
        p += tanh_fast(acc[mt][nt][r] + b1c[nt]) * w2c[nt];
      #pragma unroll
      for (int off = 1; off < 16; off <<= 1)
        p += __shfl_xor(p, off, 64);            // reduce over the 16 cols-lanes
      if (l15 == 0) sred[mt * 16 + q * 4 + r][wv] = p;
    }
  }
  __syncthreads();
  if (tid < 64) {
    float s = sred[tid][0] + sred[tid][1] + sred[tid][2] + sred[tid][3] + b2[0];
    // global-max shift dropped: softmax is shift-invariant; the 1e-8 term
    // deviation is O(1e-8/denom) ~ 3e-8 relative. s is bounded (|s| <= ~8).
    ew[row_base + tid] = __expf(s);
  }
}

// ---------------------------------------------------------------------------
// pool: one block per segment. denom = sum(ew), out = sum attn * x_row.
// ---------------------------------------------------------------------------
__global__ __launch_bounds__(256) void pool_kernel(
    const float* __restrict__ x, const float* __restrict__ ew,
    const int* __restrict__ segs, float* __restrict__ out)
{
  const int b   = blockIdx.x;
  const int tid = threadIdx.x;
  const int rs  = segs[b], re = segs[b + 1];

  __shared__ float lattn[256];
  __shared__ float red[4];

  // denominator
  float p = 0.f;
  for (int i = rs + tid; i < re; i += 256) p += ew[i];
  #pragma unroll
  for (int off = 1; off < 64; off <<= 1) p += __shfl_xor(p, off, 64);
  if ((tid & 63) == 0) red[tid >> 6] = p;
  __syncthreads();
  const float denom = red[0] + red[1] + red[2] + red[3];
  const float inv = 1.0f / (denom + 1e-8f);

  // weighted feature sum; thread owns 4 columns (float4)
  const float4* x4 = (const float4*)x;
  float4 acc = make_float4(0.f, 0.f, 0.f, 0.f);
  for (int base = rs; base < re; base += 256) {
    const int cnt = min(256, re - base);
    __syncthreads();
    if (tid < cnt) lattn[tid] = ew[base + tid] * inv;
    __syncthreads();
    #pragma unroll 4
    for (int j = 0; j < cnt; ++j) {
      const float a = lattn[j];
      const float4 xv = x4[(size_t)(base + j) * 256 + tid];
      acc.x = fmaf(a, xv.x, acc.x);
      acc.y = fmaf(a, xv.y, acc.y);
      acc.z = fmaf(a, xv.z, acc.z);
      acc.w = fmaf(a, xv.w, acc.w);
    }
  }
  ((float4*)out)[(size_t)b * 256 + tid] = acc;   // covers all outputs (poison-safe)
}

// ---------------------------------------------------------------------------
extern "C" void kernel_launch(void* const* d_in, const int* in_sizes, int n_in,
                              void* d_out, int out_size, void* d_ws, size_t ws_size,
                              hipStream_t stream)
{
  (void)in_sizes; (void)n_in; (void)out_size; (void)ws_size;
  const float* x     = (const float*)d_in[0];
  const int*   batch = (const int*)d_in[1];
  const float* W1    = (const float*)d_in[2];
  const float* b1    = (const float*)d_in[3];
  const float* W2    = (const float*)d_in[4];
  const float* b2    = (const float*)d_in[5];
  float* out = (float*)d_out;

  char* ws = (char*)d_ws;
  unsigned short* w1s = (unsigned short*)ws;            // 512 KB bf16 swizzled W1
  float* ew  = (float*)(ws + (512 << 10));              // 1 MB exp(s)
  int*   segs = (int*)(ws + (1536 << 10));              // 2049 ints

  prep_kernel <<<DIMX * HIDX / (8 * 256), 256, 0, stream>>>(W1, batch, w1s, segs);
  score_kernel<<<N_ROWS / BLK_M,          256, 0, stream>>>(x, w1s, b1, W2, b2, ew);
  pool_kernel <<<NSEG,                    256, 0, stream>>>(x, ew, segs, out);
}